// Round 1
// baseline (216.758 us; speedup 1.0000x reference)
//
#include <hip/hip_runtime.h>
#include <cstdint>
#include <cstddef>

#define B_ 2
#define N_ 2048
#define C_ 256
#define H_ 64
#define W_ 176
#define TW 16
#define NTX (W_/TW)      // 11 tiles per row
#define GSTR 20          // LDS row stride (floats) for gw tile: 80B -> 16B aligned rows

// ---------------------------------------------------------------------------
// Generic linear layer: out[r][c] = act(sum_k in[r][k]*W[k][c] + b[c])
// Block = NCOL threads (one column each), RT rows per thread.
// ---------------------------------------------------------------------------
template<int K, int NCOL, int RT, bool RELU>
__global__ __launch_bounds__(NCOL)
void linear_kernel(const float* __restrict__ in, const float* __restrict__ w,
                   const float* __restrict__ bias, float* __restrict__ out)
{
    const int c  = threadIdx.x;
    const int r0 = blockIdx.x * RT;
    float acc[RT];
    const float bv = bias[c];
#pragma unroll
    for (int r = 0; r < RT; ++r) acc[r] = bv;
    const float* inr = in + (size_t)r0 * K;
#pragma unroll 4
    for (int k = 0; k < K; ++k) {
        const float wv = w[(size_t)k * NCOL + c];
#pragma unroll
        for (int r = 0; r < RT; ++r)
            acc[r] += inr[(size_t)r * K + k] * wv;
    }
#pragma unroll
    for (int r = 0; r < RT; ++r) {
        float v = acc[r];
        if (RELU) v = fmaxf(v, 0.f);
        out[(size_t)(r0 + r) * NCOL + c] = v;
    }
}

// ---------------------------------------------------------------------------
// Per-gaussian projection params, SoA layout p[8][B*N]:
// 0:px 1:py 2:1/sx 3:1/sy 4:w(masked) 5:(sx+sy)/2 6:3sx(bbox, -1 if masked out) 7:3sy
// ---------------------------------------------------------------------------
__global__ __launch_bounds__(256)
void param_kernel(const float* __restrict__ g, const float* __restrict__ intr,
                  float* __restrict__ p)
{
    const int i = blockIdx.x * 256 + threadIdx.x;
    if (i >= B_ * N_) return;
    const float* gi = g + (size_t)i * 14;
    const float x = gi[0], y = gi[1], z = gi[2];
    const float s5 = gi[5], s6 = gi[6], wv = gi[12];
    const float k00 = intr[0], k01 = intr[1], k02 = intr[2];
    const float k10 = intr[3], k11 = intr[4], k12 = intr[5];
    const float k20 = intr[6], k21 = intr[7], k22 = intr[8];
    const float projx = k00 * x + k01 * y + k02 * z;
    const float projy = k10 * x + k11 * y + k12 * z;
    const float projz = k20 * x + k21 * y + k22 * z;
    const float inv = 1.f / (projz + 1e-6f);
    const float scale_x = (float)W_ / k02 * 0.5f;
    const float scale_y = (float)H_ / k12 * 0.5f;
    const float px = projx * inv * scale_x;
    const float py = projy * inv * scale_y;
    const bool valid = z > 0.1f;
    const bool inb = (px >= 0.f) && (px < (float)W_) && (py >= 0.f) && (py < (float)H_);
    const bool mask = valid && inb;
    const float sx = fmaxf(s5 * scale_x, 1.f);
    const float sy = fmaxf(s6 * scale_y, 1.f);
    const int NB = B_ * N_;
    p[0 * NB + i] = px;
    p[1 * NB + i] = py;
    p[2 * NB + i] = 1.f / sx;
    p[3 * NB + i] = 1.f / sy;
    p[4 * NB + i] = mask ? wv : 0.f;
    p[5 * NB + i] = 0.5f * (sx + sy);
    p[6 * NB + i] = mask ? 3.f * sx : -1.f;
    p[7 * NB + i] = 3.f * sy;
}

// ---------------------------------------------------------------------------
// Splat: block = (b, y, 16-px x-tile); 256 threads = 256 channels.
// Chunked gaussian loop: phase A computes gw for relevant gaussians into LDS
// (compacted), phase B accumulates channel dot-products.
// ---------------------------------------------------------------------------
__global__ __launch_bounds__(256)
void splat_kernel(const float* __restrict__ p, const float* __restrict__ feats,
                  float* __restrict__ out)
{
    __shared__ float gws[256 * GSTR];
    __shared__ int   list_s[256];
    __shared__ int   cnt_s;

    const int tid = threadIdx.x;
    const int bid = blockIdx.x;
    const int txi = bid % NTX;
    const int y   = (bid / NTX) % H_;
    const int b   = bid / (NTX * H_);
    const int x0  = txi * TW;
    const float fy = (float)y;
    const int NB = B_ * N_;

    float acc[TW], densp[TW], uncp[TW];
#pragma unroll
    for (int t = 0; t < TW; ++t) { acc[t] = 0.f; densp[t] = 0.f; uncp[t] = 0.f; }

    for (int chunk = 0; chunk < N_; chunk += 256) {
        const int gi = b * N_ + chunk + tid;
        const float px  = p[0 * NB + gi];
        const float py  = p[1 * NB + gi];
        const float isx = p[2 * NB + gi];
        const float isy = p[3 * NB + gi];
        const float wv  = p[4 * NB + gi];
        const float sg  = p[5 * NB + gi];
        const float rx  = p[6 * NB + gi];
        const float ry  = p[7 * NB + gi];

        __syncthreads();                 // previous phase B done with gws/list
        if (tid == 0) cnt_s = 0;
        __syncthreads();

        const float dy = fy - py;
        const bool rel = (rx > 0.f) && (fabsf(dy) < ry) &&
                         (px > (float)x0 - rx) && (px < (float)(x0 + TW - 1) + rx);
        if (rel) {
            const int slot = atomicAdd(&cnt_s, 1);
            list_s[slot] = tid;
            const float dyn = dy * isy;
            const float dy2 = dyn * dyn;
            float* grow = &gws[slot * GSTR];
#pragma unroll
            for (int t = 0; t < TW; ++t) {
                const float dxn = ((float)(x0 + t) - px) * isx;
                const float dist = dy2 + dxn * dxn;
                float gv = 0.f;
                if (dist < 9.f) gv = __expf(-0.5f * dist) * wv;
                grow[t] = gv;
                densp[t] += gv;
                uncp[t]  += gv * sg;
            }
        }
        __syncthreads();

        const int cnt = cnt_s;
        const float* fb = feats + (size_t)(b * N_ + chunk) * C_ + tid;
        for (int g = 0; g < cnt; ++g) {
            const int gidx = list_s[g];
            const float f = fb[(size_t)gidx * C_];
            const float* grow = &gws[g * GSTR];
#pragma unroll
            for (int t = 0; t < TW; ++t)
                acc[t] += grow[t] * f;
        }
    }

    // Block reduction of density, then uncertainty, through gws.
    __syncthreads();
#pragma unroll
    for (int t = 0; t < TW; ++t) gws[tid * GSTR + t] = densp[t];
    __syncthreads();
    for (int s = 128; s > 0; s >>= 1) {
        if (tid < s) {
#pragma unroll
            for (int t = 0; t < TW; ++t) gws[tid * GSTR + t] += gws[(tid + s) * GSTR + t];
        }
        __syncthreads();
    }
    float dclip[TW];
#pragma unroll
    for (int t = 0; t < TW; ++t) dclip[t] = fmaxf(gws[t], 1e-6f);
    __syncthreads();
#pragma unroll
    for (int t = 0; t < TW; ++t) gws[tid * GSTR + t] = uncp[t];
    __syncthreads();
    for (int s = 128; s > 0; s >>= 1) {
        if (tid < s) {
#pragma unroll
            for (int t = 0; t < TW; ++t) gws[tid * GSTR + t] += gws[(tid + s) * GSTR + t];
        }
        __syncthreads();
    }

    // Feature map write: channel = tid, 16 consecutive pixels -> 4x float4.
    float* o = out + (((size_t)b * C_ + tid) * H_ + y) * W_ + x0;
    float4* o4 = (float4*)o;
#pragma unroll
    for (int q = 0; q < TW / 4; ++q) {
        float4 v;
        v.x = acc[4 * q + 0] / dclip[4 * q + 0];
        v.y = acc[4 * q + 1] / dclip[4 * q + 1];
        v.z = acc[4 * q + 2] / dclip[4 * q + 2];
        v.w = acc[4 * q + 3] / dclip[4 * q + 3];
        o4[q] = v;
    }
    if (tid < TW) {
        const size_t pix = ((size_t)b * H_ + y) * W_ + x0 + tid;
        float* unc_o = out + (size_t)B_ * C_ * H_ * W_;
        float* den_o = unc_o + (size_t)B_ * H_ * W_;
        unc_o[pix] = gws[tid] / dclip[tid];
        den_o[pix] = dclip[tid];
    }
}

// ---------------------------------------------------------------------------
extern "C" void kernel_launch(void* const* d_in, const int* in_sizes, int n_in,
                              void* d_out, int out_size, void* d_ws, size_t ws_size,
                              hipStream_t stream)
{
    const float* g    = (const float*)d_in[0];
    const float* intr = (const float*)d_in[1];
    const float* w1   = (const float*)d_in[2];
    const float* b1   = (const float*)d_in[3];
    const float* w2   = (const float*)d_in[4];
    const float* b2   = (const float*)d_in[5];
    const float* w3   = (const float*)d_in[6];
    const float* b3   = (const float*)d_in[7];
    const float* fw1  = (const float*)d_in[8];
    const float* fb1  = (const float*)d_in[9];
    const float* fw2  = (const float*)d_in[10];
    const float* fb2  = (const float*)d_in[11];

    float* ws = (float*)d_ws;
    const int rows = B_ * N_;                    // 4096
    float* h1    = ws;                           // 4096*64
    float* h2    = h1 + (size_t)rows * 64;       // 4096*128
    float* feats = h2 + (size_t)rows * 128;      // 4096*256
    float* t1    = feats + (size_t)rows * 256;   // 4096*256
    float* ft    = t1 + (size_t)rows * 256;      // 4096*256
    float* prm   = ft + (size_t)rows * 256;      // 8*4096

    linear_kernel<14, 64, 8, true  ><<<dim3(rows / 8), dim3(64),  0, stream>>>(g,     w1,  b1,  h1);
    linear_kernel<64, 128, 8, true ><<<dim3(rows / 8), dim3(128), 0, stream>>>(h1,    w2,  b2,  h2);
    linear_kernel<128, 256, 8, false><<<dim3(rows / 8), dim3(256), 0, stream>>>(h2,   w3,  b3,  feats);
    linear_kernel<256, 256, 8, true ><<<dim3(rows / 8), dim3(256), 0, stream>>>(feats, fw1, fb1, t1);
    linear_kernel<256, 256, 8, false><<<dim3(rows / 8), dim3(256), 0, stream>>>(t1,   fw2, fb2, ft);

    param_kernel<<<dim3((rows + 255) / 256), dim3(256), 0, stream>>>(g, intr, prm);

    splat_kernel<<<dim3(B_ * H_ * NTX), dim3(256), 0, stream>>>(prm, ft, (float*)d_out);
}